// Round 1
// baseline (25889.084 us; speedup 1.0000x reference)
//
#include <hip/hip_runtime.h>
#include <math.h>

#define N_NODES 40000
#define N_EDGES 640000
#define N_GRAPHS 64
#define F_IN 32
#define D_EMB 256
#define D_HID 512
#define D_FC 1024
#define N_CLS 10

// ---------------------------------------------------------------------------
// edge MLP: ew = sigmoid(relu(e*w1+b1) @ w2 + b2)
// ---------------------------------------------------------------------------
__global__ void edge_mlp_kernel(const float* __restrict__ edge_attr,
                                const float* __restrict__ ep_w1, const float* __restrict__ ep_b1,
                                const float* __restrict__ ep_w2, const float* __restrict__ ep_b2,
                                float* __restrict__ ew) {
    __shared__ float w1[64], b1[64], w2[64];
    int t = threadIdx.x;
    if (t < 64) { w1[t] = ep_w1[t]; b1[t] = ep_b1[t]; w2[t] = ep_w2[t]; }
    __syncthreads();
    int e = blockIdx.x * blockDim.x + t;
    if (e >= N_EDGES) return;
    float x = edge_attr[e];
    float s = ep_b2[0];
#pragma unroll
    for (int j = 0; j < 64; ++j) s += fmaxf(x * w1[j] + b1[j], 0.f) * w2[j];
    ew[e] = 1.f / (1.f + expf(-s));
}

__global__ void deg_init_kernel(float* __restrict__ deg) {
    int i = blockIdx.x * blockDim.x + threadIdx.x;
    if (i < N_NODES) deg[i] = 1.0f;   // self-loop weight
}

__global__ void deg_add_kernel(const int* __restrict__ dst, const float* __restrict__ ew,
                               float* __restrict__ deg) {
    int e = blockIdx.x * blockDim.x + threadIdx.x;
    if (e < N_EDGES) atomicAdd(&deg[dst[e]], ew[e]);
}

__global__ void dinv_kernel(const float* __restrict__ deg, float* __restrict__ dinv,
                            float* __restrict__ nloop) {
    int i = blockIdx.x * blockDim.x + threadIdx.x;
    if (i >= N_NODES) return;
    float d = deg[i];
    float r = (d > 0.f) ? rsqrtf(fmaxf(d, 1e-12f)) : 0.f;
    dinv[i] = r;
    nloop[i] = r * r;   // norm for self loop: dinv[i]*1*dinv[i]
}

__global__ void norm_kernel(const int* __restrict__ src, const int* __restrict__ dst,
                            const float* __restrict__ ew, const float* __restrict__ dinv,
                            float* __restrict__ nrm) {
    int e = blockIdx.x * blockDim.x + threadIdx.x;
    if (e < N_EDGES) nrm[e] = dinv[src[e]] * ew[e] * dinv[dst[e]];
}

// ---------------------------------------------------------------------------
// self-loop init: T[i,:] = h[i,:] * nloop[i]   (full overwrite of T)
// ---------------------------------------------------------------------------
__global__ void selfloop_kernel(const float* __restrict__ h, const float* __restrict__ nloop,
                                float* __restrict__ T, int D4) {
    size_t t = (size_t)blockIdx.x * blockDim.x + threadIdx.x;
    size_t total = (size_t)N_NODES * D4;
    if (t >= total) return;
    int i = (int)(t / D4);
    float4 v = ((const float4*)h)[t];
    float s = nloop[i];
    v.x *= s; v.y *= s; v.z *= s; v.w *= s;
    ((float4*)T)[t] = v;
}

// ---------------------------------------------------------------------------
// scatter: T[dst,:] += h[src,:] * nrm[e]
// ---------------------------------------------------------------------------
__global__ void scatter_kernel(const float* __restrict__ h, const int* __restrict__ src,
                               const int* __restrict__ dst, const float* __restrict__ nrm,
                               float* __restrict__ T, int D) {
    int chunks = D >> 2;
    size_t t = (size_t)blockIdx.x * blockDim.x + threadIdx.x;
    if (t >= (size_t)N_EDGES * chunks) return;
    int e = (int)(t / chunks);
    int c = (int)(t % chunks);
    float n = nrm[e];
    float4 v = ((const float4*)(h + (size_t)src[e] * D))[c];
    float* out = T + (size_t)dst[e] * D + (size_t)c * 4;
    atomicAdd(out + 0, v.x * n);
    atomicAdd(out + 1, v.y * n);
    atomicAdd(out + 2, v.z * n);
    atomicAdd(out + 3, v.w * n);
}

// ---------------------------------------------------------------------------
// GEMM: C = relu(A[M,K] @ W[K,N] + bias) (+ skip)   M=N_NODES fixed
// 64x64 tile, 256 threads, 4x4 microtile, BK=16
// ---------------------------------------------------------------------------
__launch_bounds__(256)
__global__ void gemm_kernel(const float* __restrict__ A, const float* __restrict__ W,
                            const float* __restrict__ bias, const float* __restrict__ skip,
                            float* __restrict__ C, int K, int N) {
    __shared__ float Ast[16][68];   // A tile transposed [k][m], +4 pad
    __shared__ float Ws[16][68];    // W tile [k][n], +4 pad
    int t = threadIdx.x;
    int tx = t & 15, ty = t >> 4;
    int rowBase = blockIdx.x * 64;
    int colBase = blockIdx.y * 64;
    float acc[4][4] = {};

    for (int k0 = 0; k0 < K; k0 += 16) {
        int ar = t >> 2, ac = (t & 3) * 4;
        float4 av = *(const float4*)(A + (size_t)(rowBase + ar) * K + k0 + ac);
        int wr = t >> 4, wc = (t & 15) * 4;
        float4 wv = *(const float4*)(W + (size_t)(k0 + wr) * N + colBase + wc);
        __syncthreads();   // previous iteration's compute done
        Ast[ac + 0][ar] = av.x;
        Ast[ac + 1][ar] = av.y;
        Ast[ac + 2][ar] = av.z;
        Ast[ac + 3][ar] = av.w;
        *(float4*)&Ws[wr][wc] = wv;
        __syncthreads();
#pragma unroll
        for (int k = 0; k < 16; ++k) {
            float4 a = *(const float4*)&Ast[k][ty * 4];
            float4 b = *(const float4*)&Ws[k][tx * 4];
            acc[0][0] += a.x * b.x; acc[0][1] += a.x * b.y; acc[0][2] += a.x * b.z; acc[0][3] += a.x * b.w;
            acc[1][0] += a.y * b.x; acc[1][1] += a.y * b.y; acc[1][2] += a.y * b.z; acc[1][3] += a.y * b.w;
            acc[2][0] += a.z * b.x; acc[2][1] += a.z * b.y; acc[2][2] += a.z * b.z; acc[2][3] += a.z * b.w;
            acc[3][0] += a.w * b.x; acc[3][1] += a.w * b.y; acc[3][2] += a.w * b.z; acc[3][3] += a.w * b.w;
        }
    }

    int c = colBase + tx * 4;
    float4 bv = *(const float4*)(bias + c);
#pragma unroll
    for (int i = 0; i < 4; ++i) {
        size_t r = (size_t)rowBase + ty * 4 + i;
        float4 o;
        o.x = fmaxf(acc[i][0] + bv.x, 0.f);
        o.y = fmaxf(acc[i][1] + bv.y, 0.f);
        o.z = fmaxf(acc[i][2] + bv.z, 0.f);
        o.w = fmaxf(acc[i][3] + bv.w, 0.f);
        if (skip) {
            float4 s = *(const float4*)(skip + r * N + c);
            o.x += s.x; o.y += s.y; o.z += s.z; o.w += s.w;
        }
        *(float4*)(C + r * N + c) = o;
    }
}

// ---------------------------------------------------------------------------
// pooling (batch is sorted): run-length local accumulation then atomicAdd
// ---------------------------------------------------------------------------
#define NP 50
__global__ void pool_sum_kernel(const float* __restrict__ x, const int* __restrict__ batch,
                                float* __restrict__ sums) {
    int t = blockIdx.x * blockDim.x + threadIdx.x;
    int total = (N_NODES / NP) * D_HID;
    if (t >= total) return;
    int d = t % D_HID;
    int group = t / D_HID;
    int n0 = group * NP;
    float acc = 0.f;
    int g = batch[n0];
    for (int k = 0; k < NP; ++k) {
        int n = n0 + k;
        int bg = batch[n];
        if (bg != g) { atomicAdd(&sums[(size_t)g * D_HID + d], acc); acc = 0.f; g = bg; }
        acc += x[(size_t)n * D_HID + d];
    }
    atomicAdd(&sums[(size_t)g * D_HID + d], acc);
}

__global__ void cnt_kernel(const int* __restrict__ batch, float* __restrict__ cnts) {
    int n = blockIdx.x * blockDim.x + threadIdx.x;
    if (n < N_NODES) atomicAdd(&cnts[batch[n]], 1.f);
}

__global__ void zero_kernel(float* __restrict__ p, int n) {
    int i = blockIdx.x * blockDim.x + threadIdx.x;
    if (i < n) p[i] = 0.f;
}

__global__ void fc1_kernel(const float* __restrict__ sums, const float* __restrict__ cnts,
                           const float* __restrict__ W, const float* __restrict__ b,
                           float* __restrict__ out) {
    int t = blockIdx.x * blockDim.x + threadIdx.x;
    if (t >= N_GRAPHS * D_FC) return;
    int j = t % D_FC, g = t / D_FC;
    float acc = 0.f;
    const float* srow = sums + (size_t)g * D_HID;
    for (int k = 0; k < D_HID; ++k) acc += srow[k] * W[(size_t)k * D_FC + j];
    float cdiv = fmaxf(cnts[g], 1.f);
    out[t] = fmaxf(acc / cdiv + b[j], 0.f);
}

__global__ void head_kernel(const float* __restrict__ f, const float* __restrict__ W,
                            const float* __restrict__ b, float* __restrict__ out) {
    int t = blockIdx.x * blockDim.x + threadIdx.x;
    if (t >= N_GRAPHS * N_CLS) return;
    int c = t % N_CLS, g = t / N_CLS;
    float acc = b[c];
    const float* fr = f + (size_t)g * D_FC;
    for (int j = 0; j < D_FC; ++j) acc += fr[j] * W[(size_t)j * N_CLS + c];
    out[t] = acc;
}

// ---------------------------------------------------------------------------
extern "C" void kernel_launch(void* const* d_in, const int* in_sizes, int n_in,
                              void* d_out, int out_size, void* d_ws, size_t ws_size,
                              hipStream_t stream) {
    const float* x          = (const float*)d_in[0];
    const int*   edge_index = (const int*)d_in[1];   // [2][E]
    const float* edge_attr  = (const float*)d_in[2];
    const int*   batch      = (const int*)d_in[3];
    const float* emb_w1 = (const float*)d_in[4];
    const float* emb_b1 = (const float*)d_in[5];
    const float* emb_w2 = (const float*)d_in[6];
    const float* emb_b2 = (const float*)d_in[7];
    const float* ep_w1  = (const float*)d_in[8];
    const float* ep_b1  = (const float*)d_in[9];
    const float* ep_w2  = (const float*)d_in[10];
    const float* ep_b2  = (const float*)d_in[11];
    const float* w_c[6] = { (const float*)d_in[12], (const float*)d_in[14], (const float*)d_in[16],
                            (const float*)d_in[18], (const float*)d_in[20], (const float*)d_in[22] };
    const float* b_c[6] = { (const float*)d_in[13], (const float*)d_in[15], (const float*)d_in[17],
                            (const float*)d_in[19], (const float*)d_in[21], (const float*)d_in[23] };
    const float* fc1_w  = (const float*)d_in[24];
    const float* fc1_b  = (const float*)d_in[25];
    const float* head_w = (const float*)d_in[26];
    const float* head_b = (const float*)d_in[27];
    float* out = (float*)d_out;

    const int* src = edge_index;            // edge_index[0]
    const int* dst = edge_index + N_EDGES;  // edge_index[1]

    float* ws    = (float*)d_ws;
    float* ew    = ws;
    float* nrm   = ew + N_EDGES;
    float* deg   = nrm + N_EDGES;
    float* dinv  = deg + N_NODES;
    float* nloop = dinv + N_NODES;
    float* B1 = nloop + N_NODES;
    float* B2 = B1 + (size_t)N_NODES * D_HID;
    float* B3 = B2 + (size_t)N_NODES * D_HID;
    float* sums = B3 + (size_t)N_NODES * D_HID;  // 64*512
    float* cnts = sums + N_GRAPHS * D_HID;       // 64
    float* f1o  = cnts + N_GRAPHS;               // 64*1024

    const int TB = 256;
    // --- edge weights + norm ---
    edge_mlp_kernel<<<(N_EDGES + TB - 1) / TB, TB, 0, stream>>>(edge_attr, ep_w1, ep_b1, ep_w2, ep_b2, ew);
    deg_init_kernel<<<(N_NODES + TB - 1) / TB, TB, 0, stream>>>(deg);
    deg_add_kernel<<<(N_EDGES + TB - 1) / TB, TB, 0, stream>>>(dst, ew, deg);
    dinv_kernel<<<(N_NODES + TB - 1) / TB, TB, 0, stream>>>(deg, dinv, nloop);
    norm_kernel<<<(N_EDGES + TB - 1) / TB, TB, 0, stream>>>(src, dst, ew, dinv, nrm);

    // --- embedding MLP: B1 = relu(x@emb_w1+b1); B3 = relu(B1@emb_w2+b2) ---
    gemm_kernel<<<dim3(N_NODES / 64, D_EMB / 64), 256, 0, stream>>>(x, emb_w1, emb_b1, nullptr, B1, F_IN, D_EMB);
    gemm_kernel<<<dim3(N_NODES / 64, D_EMB / 64), 256, 0, stream>>>(B1, emb_w2, emb_b2, nullptr, B3, D_EMB, D_EMB);

    size_t sl256 = (size_t)N_NODES * (D_EMB / 4), sc256 = (size_t)N_EDGES * (D_EMB / 4);
    size_t sl512 = (size_t)N_NODES * (D_HID / 4), sc512 = (size_t)N_EDGES * (D_HID / 4);

    // --- conv1 (aggregate on 256-wide input, then GEMM w/ fused bias+relu) ---
    selfloop_kernel<<<(sl256 + TB - 1) / TB, TB, 0, stream>>>(B3, nloop, B1, D_EMB / 4);
    scatter_kernel<<<(sc256 + TB - 1) / TB, TB, 0, stream>>>(B3, src, dst, nrm, B1, D_EMB);
    gemm_kernel<<<dim3(N_NODES / 64, D_HID / 64), 256, 0, stream>>>(B1, w_c[0], b_c[0], nullptr, B2, D_EMB, D_HID);
    // --- conv2 ---
    selfloop_kernel<<<(sl512 + TB - 1) / TB, TB, 0, stream>>>(B2, nloop, B1, D_HID / 4);
    scatter_kernel<<<(sc512 + TB - 1) / TB, TB, 0, stream>>>(B2, src, dst, nrm, B1, D_HID);
    gemm_kernel<<<dim3(N_NODES / 64, D_HID / 64), 256, 0, stream>>>(B1, w_c[1], b_c[1], nullptr, B3, D_HID, D_HID);
    // --- conv3 (skip add into B2) ---
    selfloop_kernel<<<(sl512 + TB - 1) / TB, TB, 0, stream>>>(B3, nloop, B1, D_HID / 4);
    scatter_kernel<<<(sc512 + TB - 1) / TB, TB, 0, stream>>>(B3, src, dst, nrm, B1, D_HID);
    gemm_kernel<<<dim3(N_NODES / 64, D_HID / 64), 256, 0, stream>>>(B1, w_c[2], b_c[2], B2, B2, D_HID, D_HID);
    // --- conv4 ---
    selfloop_kernel<<<(sl512 + TB - 1) / TB, TB, 0, stream>>>(B2, nloop, B1, D_HID / 4);
    scatter_kernel<<<(sc512 + TB - 1) / TB, TB, 0, stream>>>(B2, src, dst, nrm, B1, D_HID);
    gemm_kernel<<<dim3(N_NODES / 64, D_HID / 64), 256, 0, stream>>>(B1, w_c[3], b_c[3], nullptr, B3, D_HID, D_HID);
    // --- conv5 ---
    selfloop_kernel<<<(sl512 + TB - 1) / TB, TB, 0, stream>>>(B3, nloop, B1, D_HID / 4);
    scatter_kernel<<<(sc512 + TB - 1) / TB, TB, 0, stream>>>(B3, src, dst, nrm, B1, D_HID);
    gemm_kernel<<<dim3(N_NODES / 64, D_HID / 64), 256, 0, stream>>>(B1, w_c[4], b_c[4], nullptr, B3, D_HID, D_HID);
    // --- conv6 (skip add from B2, out B3) ---
    selfloop_kernel<<<(sl512 + TB - 1) / TB, TB, 0, stream>>>(B3, nloop, B1, D_HID / 4);
    scatter_kernel<<<(sc512 + TB - 1) / TB, TB, 0, stream>>>(B3, src, dst, nrm, B1, D_HID);
    gemm_kernel<<<dim3(N_NODES / 64, D_HID / 64), 256, 0, stream>>>(B1, w_c[5], b_c[5], B2, B3, D_HID, D_HID);

    // --- pool + head ---
    zero_kernel<<<(N_GRAPHS * D_HID + N_GRAPHS + TB - 1) / TB, TB, 0, stream>>>(sums, N_GRAPHS * D_HID + N_GRAPHS);
    pool_sum_kernel<<<((N_NODES / NP) * D_HID + TB - 1) / TB, TB, 0, stream>>>(B3, batch, sums);
    cnt_kernel<<<(N_NODES + TB - 1) / TB, TB, 0, stream>>>(batch, cnts);
    fc1_kernel<<<(N_GRAPHS * D_FC + TB - 1) / TB, TB, 0, stream>>>(sums, cnts, fc1_w, fc1_b, f1o);
    head_kernel<<<(N_GRAPHS * N_CLS + TB - 1) / TB, TB, 0, stream>>>(f1o, head_w, head_b, out);
}

// Round 2
// 3604.025 us; speedup vs baseline: 7.1834x; 7.1834x over previous
//
#include <hip/hip_runtime.h>
#include <math.h>

#define N_NODES 40000
#define N_EDGES 640000
#define N_GRAPHS 64
#define F_IN 32
#define D_EMB 256
#define D_HID 512
#define D_FC 1024
#define N_CLS 10

// ---------------------------------------------------------------------------
// edge MLP: ew = sigmoid(relu(e*w1+b1) @ w2 + b2)
// ---------------------------------------------------------------------------
__global__ void edge_mlp_kernel(const float* __restrict__ edge_attr,
                                const float* __restrict__ ep_w1, const float* __restrict__ ep_b1,
                                const float* __restrict__ ep_w2, const float* __restrict__ ep_b2,
                                float* __restrict__ ew) {
    __shared__ float w1[64], b1[64], w2[64];
    int t = threadIdx.x;
    if (t < 64) { w1[t] = ep_w1[t]; b1[t] = ep_b1[t]; w2[t] = ep_w2[t]; }
    __syncthreads();
    int e = blockIdx.x * blockDim.x + t;
    if (e >= N_EDGES) return;
    float x = edge_attr[e];
    float s = ep_b2[0];
#pragma unroll
    for (int j = 0; j < 64; ++j) s += fmaxf(x * w1[j] + b1[j], 0.f) * w2[j];
    ew[e] = 1.f / (1.f + expf(-s));
}

__global__ void zero_int_kernel(int* __restrict__ p, int n) {
    int i = blockIdx.x * blockDim.x + threadIdx.x;
    if (i < n) p[i] = 0;
}

__global__ void deg_init_kernel(float* __restrict__ deg) {
    int i = blockIdx.x * blockDim.x + threadIdx.x;
    if (i < N_NODES) deg[i] = 1.0f;   // self-loop weight
}

__global__ void deg_add_kernel(const int* __restrict__ dst, const float* __restrict__ ew,
                               float* __restrict__ deg, int* __restrict__ cnt) {
    int e = blockIdx.x * blockDim.x + threadIdx.x;
    if (e >= N_EDGES) return;
    int d = dst[e];
    atomicAdd(&deg[d], ew[e]);
    atomicAdd(&cnt[d], 1);
}

__global__ void dinv_kernel(const float* __restrict__ deg, float* __restrict__ dinv,
                            float* __restrict__ nloop) {
    int i = blockIdx.x * blockDim.x + threadIdx.x;
    if (i >= N_NODES) return;
    float d = deg[i];
    float r = (d > 0.f) ? rsqrtf(fmaxf(d, 1e-12f)) : 0.f;
    dinv[i] = r;
    nloop[i] = r * r;   // norm for self loop: dinv[i]*1*dinv[i]
}

// exclusive prefix sum of cnt[N_NODES] -> rowptr[N_NODES+1]; single block 1024
__global__ void scan_kernel(const int* __restrict__ cnt, int* __restrict__ rowptr) {
    __shared__ int part[1024];
    int t = threadIdx.x;
    const int PER = (N_NODES + 1023) / 1024;   // 40
    int base = t * PER;
    int s = 0;
    for (int k = 0; k < PER; ++k) { int i = base + k; if (i < N_NODES) s += cnt[i]; }
    part[t] = s;
    __syncthreads();
    for (int off = 1; off < 1024; off <<= 1) {
        int v = (t >= off) ? part[t - off] : 0;
        __syncthreads();
        part[t] += v;
        __syncthreads();
    }
    int run = (t == 0) ? 0 : part[t - 1];
    for (int k = 0; k < PER; ++k) {
        int i = base + k;
        if (i < N_NODES) { rowptr[i] = run; run += cnt[i]; }
    }
    if (t == 1023) rowptr[N_NODES] = run;
}

// fill CSR: for each edge, slot = rowptr[dst]+cursor[dst]++; col=src, val=nrm
__global__ void fill_csr_kernel(const int* __restrict__ src, const int* __restrict__ dst,
                                const float* __restrict__ ew, const float* __restrict__ dinv,
                                const int* __restrict__ rowptr, int* __restrict__ cursor,
                                int* __restrict__ col, float* __restrict__ val) {
    int e = blockIdx.x * blockDim.x + threadIdx.x;
    if (e >= N_EDGES) return;
    int d = dst[e];
    int s = src[e];
    float n = dinv[s] * ew[e] * dinv[d];
    int p = rowptr[d] + atomicAdd(&cursor[d], 1);
    col[p] = s;
    val[p] = n;
}

// ---------------------------------------------------------------------------
// gather aggregation: out[i,:] = h[i,:]*nloop[i] + sum_j h[col[j],:]*val[j]
// one block per node, blockDim = D/4 threads, each owns one float4 chunk
// ---------------------------------------------------------------------------
__global__ void gather_kernel(const float* __restrict__ h, const int* __restrict__ rowptr,
                              const int* __restrict__ col, const float* __restrict__ val,
                              const float* __restrict__ nloop, float* __restrict__ out,
                              int D4) {
    int i = blockIdx.x;
    int c = threadIdx.x;
    const float4* h4 = (const float4*)h;
    float4 acc = h4[(size_t)i * D4 + c];
    float sl = nloop[i];
    acc.x *= sl; acc.y *= sl; acc.z *= sl; acc.w *= sl;
    int beg = rowptr[i], end = rowptr[i + 1];
    for (int j = beg; j < end; ++j) {
        int s = col[j];
        float v = val[j];
        float4 x = h4[(size_t)s * D4 + c];
        acc.x += x.x * v; acc.y += x.y * v; acc.z += x.z * v; acc.w += x.w * v;
    }
    ((float4*)out)[(size_t)i * D4 + c] = acc;
}

// ---------------------------------------------------------------------------
// GEMM: C = relu(A[M,K] @ W[K,N] + bias) (+ skip)   M=N_NODES fixed
// 64x64 tile, 256 threads, 4x4 microtile, BK=16
// ---------------------------------------------------------------------------
__launch_bounds__(256)
__global__ void gemm_kernel(const float* __restrict__ A, const float* __restrict__ W,
                            const float* __restrict__ bias, const float* __restrict__ skip,
                            float* __restrict__ C, int K, int N) {
    __shared__ float Ast[16][68];   // A tile transposed [k][m], +4 pad
    __shared__ float Ws[16][68];    // W tile [k][n], +4 pad
    int t = threadIdx.x;
    int tx = t & 15, ty = t >> 4;
    int rowBase = blockIdx.x * 64;
    int colBase = blockIdx.y * 64;
    float acc[4][4] = {};

    for (int k0 = 0; k0 < K; k0 += 16) {
        int ar = t >> 2, ac = (t & 3) * 4;
        float4 av = *(const float4*)(A + (size_t)(rowBase + ar) * K + k0 + ac);
        int wr = t >> 4, wc = (t & 15) * 4;
        float4 wv = *(const float4*)(W + (size_t)(k0 + wr) * N + colBase + wc);
        __syncthreads();
        Ast[ac + 0][ar] = av.x;
        Ast[ac + 1][ar] = av.y;
        Ast[ac + 2][ar] = av.z;
        Ast[ac + 3][ar] = av.w;
        *(float4*)&Ws[wr][wc] = wv;
        __syncthreads();
#pragma unroll
        for (int k = 0; k < 16; ++k) {
            float4 a = *(const float4*)&Ast[k][ty * 4];
            float4 b = *(const float4*)&Ws[k][tx * 4];
            acc[0][0] += a.x * b.x; acc[0][1] += a.x * b.y; acc[0][2] += a.x * b.z; acc[0][3] += a.x * b.w;
            acc[1][0] += a.y * b.x; acc[1][1] += a.y * b.y; acc[1][2] += a.y * b.z; acc[1][3] += a.y * b.w;
            acc[2][0] += a.z * b.x; acc[2][1] += a.z * b.y; acc[2][2] += a.z * b.z; acc[2][3] += a.z * b.w;
            acc[3][0] += a.w * b.x; acc[3][1] += a.w * b.y; acc[3][2] += a.w * b.z; acc[3][3] += a.w * b.w;
        }
    }

    int c = colBase + tx * 4;
    float4 bv = *(const float4*)(bias + c);
#pragma unroll
    for (int i = 0; i < 4; ++i) {
        size_t r = (size_t)rowBase + ty * 4 + i;
        float4 o;
        o.x = fmaxf(acc[i][0] + bv.x, 0.f);
        o.y = fmaxf(acc[i][1] + bv.y, 0.f);
        o.z = fmaxf(acc[i][2] + bv.z, 0.f);
        o.w = fmaxf(acc[i][3] + bv.w, 0.f);
        if (skip) {
            float4 s = *(const float4*)(skip + r * N + c);
            o.x += s.x; o.y += s.y; o.z += s.z; o.w += s.w;
        }
        *(float4*)(C + r * N + c) = o;
    }
}

// ---------------------------------------------------------------------------
// pooling (batch is sorted): run-length local accumulation then atomicAdd
// ---------------------------------------------------------------------------
#define NP 50
__global__ void pool_sum_kernel(const float* __restrict__ x, const int* __restrict__ batch,
                                float* __restrict__ sums) {
    int t = blockIdx.x * blockDim.x + threadIdx.x;
    int total = (N_NODES / NP) * D_HID;
    if (t >= total) return;
    int d = t % D_HID;
    int group = t / D_HID;
    int n0 = group * NP;
    float acc = 0.f;
    int g = batch[n0];
    for (int k = 0; k < NP; ++k) {
        int n = n0 + k;
        int bg = batch[n];
        if (bg != g) { atomicAdd(&sums[(size_t)g * D_HID + d], acc); acc = 0.f; g = bg; }
        acc += x[(size_t)n * D_HID + d];
    }
    atomicAdd(&sums[(size_t)g * D_HID + d], acc);
}

__global__ void cnt_kernel(const int* __restrict__ batch, float* __restrict__ cnts) {
    int n = blockIdx.x * blockDim.x + threadIdx.x;
    if (n < N_NODES) atomicAdd(&cnts[batch[n]], 1.f);
}

__global__ void zero_kernel(float* __restrict__ p, int n) {
    int i = blockIdx.x * blockDim.x + threadIdx.x;
    if (i < n) p[i] = 0.f;
}

__global__ void fc1_kernel(const float* __restrict__ sums, const float* __restrict__ cnts,
                           const float* __restrict__ W, const float* __restrict__ b,
                           float* __restrict__ out) {
    int t = blockIdx.x * blockDim.x + threadIdx.x;
    if (t >= N_GRAPHS * D_FC) return;
    int j = t % D_FC, g = t / D_FC;
    float acc = 0.f;
    const float* srow = sums + (size_t)g * D_HID;
    for (int k = 0; k < D_HID; ++k) acc += srow[k] * W[(size_t)k * D_FC + j];
    float cdiv = fmaxf(cnts[g], 1.f);
    out[t] = fmaxf(acc / cdiv + b[j], 0.f);
}

__global__ void head_kernel(const float* __restrict__ f, const float* __restrict__ W,
                            const float* __restrict__ b, float* __restrict__ out) {
    int t = blockIdx.x * blockDim.x + threadIdx.x;
    if (t >= N_GRAPHS * N_CLS) return;
    int c = t % N_CLS, g = t / N_CLS;
    float acc = b[c];
    const float* fr = f + (size_t)g * D_FC;
    for (int j = 0; j < D_FC; ++j) acc += fr[j] * W[(size_t)j * N_CLS + c];
    out[t] = acc;
}

// ---------------------------------------------------------------------------
extern "C" void kernel_launch(void* const* d_in, const int* in_sizes, int n_in,
                              void* d_out, int out_size, void* d_ws, size_t ws_size,
                              hipStream_t stream) {
    const float* x          = (const float*)d_in[0];
    const int*   edge_index = (const int*)d_in[1];   // [2][E]
    const float* edge_attr  = (const float*)d_in[2];
    const int*   batch      = (const int*)d_in[3];
    const float* emb_w1 = (const float*)d_in[4];
    const float* emb_b1 = (const float*)d_in[5];
    const float* emb_w2 = (const float*)d_in[6];
    const float* emb_b2 = (const float*)d_in[7];
    const float* ep_w1  = (const float*)d_in[8];
    const float* ep_b1  = (const float*)d_in[9];
    const float* ep_w2  = (const float*)d_in[10];
    const float* ep_b2  = (const float*)d_in[11];
    const float* w_c[6] = { (const float*)d_in[12], (const float*)d_in[14], (const float*)d_in[16],
                            (const float*)d_in[18], (const float*)d_in[20], (const float*)d_in[22] };
    const float* b_c[6] = { (const float*)d_in[13], (const float*)d_in[15], (const float*)d_in[17],
                            (const float*)d_in[19], (const float*)d_in[21], (const float*)d_in[23] };
    const float* fc1_w  = (const float*)d_in[24];
    const float* fc1_b  = (const float*)d_in[25];
    const float* head_w = (const float*)d_in[26];
    const float* head_b = (const float*)d_in[27];
    float* out = (float*)d_out;

    const int* src = edge_index;            // edge_index[0]
    const int* dst = edge_index + N_EDGES;  // edge_index[1]

    float* ws    = (float*)d_ws;
    float* ew    = ws;                           // E
    float* deg   = ew + N_EDGES;                 // N
    float* dinv  = deg + N_NODES;                // N
    float* nloop = dinv + N_NODES;               // N
    float* val   = nloop + N_NODES;              // E  (CSR values)
    int*   cnt    = (int*)(val + N_EDGES);       // N
    int*   cursor = cnt + N_NODES;               // N
    int*   rowptr = cursor + N_NODES;            // N+1
    int*   col    = rowptr + N_NODES + 1;        // E  (CSR col = src)
    float* B1 = (float*)(col + N_EDGES);
    float* B2 = B1 + (size_t)N_NODES * D_HID;
    float* B3 = B2 + (size_t)N_NODES * D_HID;
    float* sums = B3 + (size_t)N_NODES * D_HID;  // 64*512
    float* cnts = sums + N_GRAPHS * D_HID;       // 64
    float* f1o  = cnts + N_GRAPHS;               // 64*1024

    const int TB = 256;
    const int EB = (N_EDGES + TB - 1) / TB;
    const int NB = (N_NODES + TB - 1) / TB;

    // --- edge weights, degrees, CSR build ---
    edge_mlp_kernel<<<EB, TB, 0, stream>>>(edge_attr, ep_w1, ep_b1, ep_w2, ep_b2, ew);
    deg_init_kernel<<<NB, TB, 0, stream>>>(deg);
    zero_int_kernel<<<(2 * N_NODES + TB - 1) / TB, TB, 0, stream>>>(cnt, 2 * N_NODES); // cnt + cursor
    deg_add_kernel<<<EB, TB, 0, stream>>>(dst, ew, deg, cnt);
    dinv_kernel<<<NB, TB, 0, stream>>>(deg, dinv, nloop);
    scan_kernel<<<1, 1024, 0, stream>>>(cnt, rowptr);
    fill_csr_kernel<<<EB, TB, 0, stream>>>(src, dst, ew, dinv, rowptr, cursor, col, val);

    // --- embedding MLP: B1 = relu(x@emb_w1+b1); B3 = relu(B1@emb_w2+b2) ---
    gemm_kernel<<<dim3(N_NODES / 64, D_EMB / 64), 256, 0, stream>>>(x, emb_w1, emb_b1, nullptr, B1, F_IN, D_EMB);
    gemm_kernel<<<dim3(N_NODES / 64, D_EMB / 64), 256, 0, stream>>>(B1, emb_w2, emb_b2, nullptr, B3, D_EMB, D_EMB);

    // --- conv1: aggregate(256-wide) then GEMM 256->512 ---
    gather_kernel<<<N_NODES, D_EMB / 4, 0, stream>>>(B3, rowptr, col, val, nloop, B1, D_EMB / 4);
    gemm_kernel<<<dim3(N_NODES / 64, D_HID / 64), 256, 0, stream>>>(B1, w_c[0], b_c[0], nullptr, B2, D_EMB, D_HID);
    // --- conv2 ---
    gather_kernel<<<N_NODES, D_HID / 4, 0, stream>>>(B2, rowptr, col, val, nloop, B1, D_HID / 4);
    gemm_kernel<<<dim3(N_NODES / 64, D_HID / 64), 256, 0, stream>>>(B1, w_c[1], b_c[1], nullptr, B3, D_HID, D_HID);
    // --- conv3 (skip add into B2) ---
    gather_kernel<<<N_NODES, D_HID / 4, 0, stream>>>(B3, rowptr, col, val, nloop, B1, D_HID / 4);
    gemm_kernel<<<dim3(N_NODES / 64, D_HID / 64), 256, 0, stream>>>(B1, w_c[2], b_c[2], B2, B2, D_HID, D_HID);
    // --- conv4 ---
    gather_kernel<<<N_NODES, D_HID / 4, 0, stream>>>(B2, rowptr, col, val, nloop, B1, D_HID / 4);
    gemm_kernel<<<dim3(N_NODES / 64, D_HID / 64), 256, 0, stream>>>(B1, w_c[3], b_c[3], nullptr, B3, D_HID, D_HID);
    // --- conv5 ---
    gather_kernel<<<N_NODES, D_HID / 4, 0, stream>>>(B3, rowptr, col, val, nloop, B1, D_HID / 4);
    gemm_kernel<<<dim3(N_NODES / 64, D_HID / 64), 256, 0, stream>>>(B1, w_c[4], b_c[4], nullptr, B3, D_HID, D_HID);
    // --- conv6 (skip add from B2, out B3) ---
    gather_kernel<<<N_NODES, D_HID / 4, 0, stream>>>(B3, rowptr, col, val, nloop, B1, D_HID / 4);
    gemm_kernel<<<dim3(N_NODES / 64, D_HID / 64), 256, 0, stream>>>(B1, w_c[5], b_c[5], B2, B3, D_HID, D_HID);

    // --- pool + head ---
    zero_kernel<<<(N_GRAPHS * D_HID + N_GRAPHS + TB - 1) / TB, TB, 0, stream>>>(sums, N_GRAPHS * D_HID + N_GRAPHS);
    pool_sum_kernel<<<((N_NODES / NP) * D_HID + TB - 1) / TB, TB, 0, stream>>>(B3, batch, sums);
    cnt_kernel<<<NB, TB, 0, stream>>>(batch, cnts);
    fc1_kernel<<<(N_GRAPHS * D_FC + TB - 1) / TB, TB, 0, stream>>>(sums, cnts, fc1_w, fc1_b, f1o);
    head_kernel<<<(N_GRAPHS * N_CLS + TB - 1) / TB, TB, 0, stream>>>(f1o, head_w, head_b, out);
}

// Round 3
// 1797.236 us; speedup vs baseline: 14.4049x; 2.0053x over previous
//
#include <hip/hip_runtime.h>
#include <math.h>

#define N_NODES 40000
#define MP      40064   // padded to 128*313
#define N_EDGES 640000
#define N_GRAPHS 64
#define F_IN 32
#define D_EMB 256
#define D_HID 512
#define D_FC 1024
#define N_CLS 10

typedef short bf16x8 __attribute__((ext_vector_type(8)));
typedef float f32x4  __attribute__((ext_vector_type(4)));

__device__ __forceinline__ float bf2f(unsigned short u) {
    return __uint_as_float(((unsigned)u) << 16);
}
__device__ __forceinline__ unsigned short f2bf(float f) {
    unsigned u = __float_as_uint(f);
    return (unsigned short)((u + 0x7FFF + ((u >> 16) & 1)) >> 16);
}
__device__ __forceinline__ void async16(void* lds, const void* g) {
    __builtin_amdgcn_global_load_lds((const __attribute__((address_space(1))) void*)g,
                                     (__attribute__((address_space(3))) void*)lds, 16, 0, 0);
}

// ---------------------------------------------------------------------------
// edge MLP: ew = sigmoid(relu(e*w1+b1) @ w2 + b2)
// ---------------------------------------------------------------------------
__global__ void edge_mlp_kernel(const float* __restrict__ edge_attr,
                                const float* __restrict__ ep_w1, const float* __restrict__ ep_b1,
                                const float* __restrict__ ep_w2, const float* __restrict__ ep_b2,
                                float* __restrict__ ew) {
    __shared__ float w1[64], b1[64], w2[64];
    int t = threadIdx.x;
    if (t < 64) { w1[t] = ep_w1[t]; b1[t] = ep_b1[t]; w2[t] = ep_w2[t]; }
    __syncthreads();
    int e = blockIdx.x * blockDim.x + t;
    if (e >= N_EDGES) return;
    float x = edge_attr[e];
    float s = ep_b2[0];
#pragma unroll
    for (int j = 0; j < 64; ++j) s += fmaxf(x * w1[j] + b1[j], 0.f) * w2[j];
    ew[e] = 1.f / (1.f + expf(-s));
}

__global__ void zero_int_kernel(int* __restrict__ p, int n) {
    int i = blockIdx.x * blockDim.x + threadIdx.x;
    if (i < n) p[i] = 0;
}

__global__ void deg_init_kernel(float* __restrict__ deg) {
    int i = blockIdx.x * blockDim.x + threadIdx.x;
    if (i < N_NODES) deg[i] = 1.0f;
}

__global__ void deg_add_kernel(const int* __restrict__ dst, const float* __restrict__ ew,
                               float* __restrict__ deg, int* __restrict__ cnt) {
    int e = blockIdx.x * blockDim.x + threadIdx.x;
    if (e >= N_EDGES) return;
    int d = dst[e];
    atomicAdd(&deg[d], ew[e]);
    atomicAdd(&cnt[d], 1);
}

__global__ void dinv_kernel(const float* __restrict__ deg, float* __restrict__ dinv,
                            float* __restrict__ nloop) {
    int i = blockIdx.x * blockDim.x + threadIdx.x;
    if (i >= N_NODES) return;
    float d = deg[i];
    float r = (d > 0.f) ? rsqrtf(fmaxf(d, 1e-12f)) : 0.f;
    dinv[i] = r;
    nloop[i] = r * r;
}

__global__ void scan_kernel(const int* __restrict__ cnt, int* __restrict__ rowptr) {
    __shared__ int part[1024];
    int t = threadIdx.x;
    const int PER = (N_NODES + 1023) / 1024;
    int base = t * PER;
    int s = 0;
    for (int k = 0; k < PER; ++k) { int i = base + k; if (i < N_NODES) s += cnt[i]; }
    part[t] = s;
    __syncthreads();
    for (int off = 1; off < 1024; off <<= 1) {
        int v = (t >= off) ? part[t - off] : 0;
        __syncthreads();
        part[t] += v;
        __syncthreads();
    }
    int run = (t == 0) ? 0 : part[t - 1];
    for (int k = 0; k < PER; ++k) {
        int i = base + k;
        if (i < N_NODES) { rowptr[i] = run; run += cnt[i]; }
    }
    if (t == 1023) rowptr[N_NODES] = run;
}

__global__ void fill_csr_kernel(const int* __restrict__ src, const int* __restrict__ dst,
                                const float* __restrict__ ew, const float* __restrict__ dinv,
                                const int* __restrict__ rowptr, int* __restrict__ cursor,
                                int* __restrict__ col, float* __restrict__ val) {
    int e = blockIdx.x * blockDim.x + threadIdx.x;
    if (e >= N_EDGES) return;
    int d = dst[e];
    int s = src[e];
    float n = dinv[s] * ew[e] * dinv[d];
    int p = rowptr[d] + atomicAdd(&cursor[d], 1);
    col[p] = s;
    val[p] = n;
}

// ---------------------------------------------------------------------------
// weight prep: W[K][N] fp32 -> Wth/Wtl [N][K] bf16 (hi + lo split, transposed)
// ---------------------------------------------------------------------------
__global__ void wprep_kernel(const float* __restrict__ W, unsigned short* __restrict__ Wth,
                             unsigned short* __restrict__ Wtl, int K, int N) {
    int idx = blockIdx.x * blockDim.x + threadIdx.x;
    if (idx >= K * N) return;
    int k = idx / N, n = idx % N;
    float w = W[idx];
    unsigned short hi = f2bf(w);
    unsigned short lo = f2bf(w - bf2f(hi));
    Wth[(size_t)n * K + k] = hi;
    Wtl[(size_t)n * K + k] = lo;
}

// x fp32 [N_NODES][F_IN] -> bf16 [MP][F_IN] (pad rows zeroed)
__global__ void xprep_kernel(const float* __restrict__ x, unsigned short* __restrict__ xb) {
    int idx = blockIdx.x * blockDim.x + threadIdx.x;
    if (idx >= MP * F_IN) return;
    int row = idx / F_IN;
    xb[idx] = (row < N_NODES) ? f2bf(x[idx]) : (unsigned short)0;
}

// ---------------------------------------------------------------------------
// MFMA GEMM: C[MP][N] = relu(A[MP][K]_bf16 @ (Wh+Wl)[K][N] + bias) (+skip)
// Wh/Wl given transposed [N][K]. 128x128 tile, 256 thr (4 waves), BK=32.
// ---------------------------------------------------------------------------
__launch_bounds__(256)
__global__ void mfma_gemm(const unsigned short* __restrict__ A,
                          const unsigned short* __restrict__ Wh,
                          const unsigned short* __restrict__ Wl,
                          const float* __restrict__ bias,
                          const unsigned short* __restrict__ skip,
                          unsigned short* __restrict__ C, int K, int N) {
    __shared__ __align__(16) unsigned short As[128 * 32];
    __shared__ __align__(16) unsigned short Hs[128 * 32];
    __shared__ __align__(16) unsigned short Ls[128 * 32];
    int t = threadIdx.x;
    int lane = t & 63;
    int wave = t >> 6;
    int wr = wave >> 1, wc = wave & 1;       // 2x2 waves over 128x128
    int rowBase = blockIdx.x * 128;
    int colBase = blockIdx.y * 128;

    // staging: each wave stages 32 rows (2 instrs of 16 rows) of each tile
    int r0 = wave * 32;
    int rr = r0 + (lane >> 2);               // row handled by this lane
    int selem = (lane & 3) * 8;              // bf16 elem offset within 32-elem row

    int quad = lane >> 4;
    int mrow = lane & 15;

    f32x4 acc[4][4] = {};

    for (int k0 = 0; k0 < K; k0 += 32) {
        const unsigned short* gA = A + (size_t)(rowBase + rr) * K + k0 + selem;
        const unsigned short* gH = Wh + (size_t)(colBase + rr) * K + k0 + selem;
        const unsigned short* gL = Wl + (size_t)(colBase + rr) * K + k0 + selem;
        async16(&As[r0 * 32], gA);
        async16(&As[(r0 + 16) * 32], gA + (size_t)16 * K);
        async16(&Hs[r0 * 32], gH);
        async16(&Hs[(r0 + 16) * 32], gH + (size_t)16 * K);
        async16(&Ls[r0 * 32], gL);
        async16(&Ls[(r0 + 16) * 32], gL + (size_t)16 * K);
        __syncthreads();   // drains vmcnt (loads visible)

        bf16x8 af[4], hf[4], lf[4];
#pragma unroll
        for (int i = 0; i < 4; ++i) {
            af[i] = *(const bf16x8*)&As[(wr * 64 + i * 16 + mrow) * 32 + quad * 8];
            hf[i] = *(const bf16x8*)&Hs[(wc * 64 + i * 16 + mrow) * 32 + quad * 8];
            lf[i] = *(const bf16x8*)&Ls[(wc * 64 + i * 16 + mrow) * 32 + quad * 8];
        }
#pragma unroll
        for (int i = 0; i < 4; ++i)
#pragma unroll
            for (int j = 0; j < 4; ++j) {
                acc[i][j] = __builtin_amdgcn_mfma_f32_16x16x32_bf16(af[i], hf[j], acc[i][j], 0, 0, 0);
                acc[i][j] = __builtin_amdgcn_mfma_f32_16x16x32_bf16(af[i], lf[j], acc[i][j], 0, 0, 0);
            }
        __syncthreads();   // all waves done reading before next-step overwrite
    }

    // epilogue: C/D layout col=lane&15, row=quad*4+reg
    int col0 = colBase + wc * 64 + mrow;
#pragma unroll
    for (int j = 0; j < 4; ++j) {
        int col = col0 + j * 16;
        float bv = bias[col];
#pragma unroll
        for (int i = 0; i < 4; ++i) {
#pragma unroll
            for (int r = 0; r < 4; ++r) {
                size_t row = (size_t)rowBase + wr * 64 + i * 16 + quad * 4 + r;
                float v = fmaxf(acc[i][j][r] + bv, 0.f);
                if (skip) v += bf2f(skip[row * N + col]);
                C[row * N + col] = f2bf(v);
            }
        }
    }
}

// ---------------------------------------------------------------------------
// gather aggregation (bf16 in/out, fp32 accum): one wave per node
// out[i,:] = h[i,:]*nloop[i] + sum_j h[col[j],:]*val[j]
// ---------------------------------------------------------------------------
template <int D>
__global__ void gather_bf16(const unsigned short* __restrict__ h, const int* __restrict__ rowptr,
                            const int* __restrict__ col, const float* __restrict__ val,
                            const float* __restrict__ nloop, unsigned short* __restrict__ out) {
    constexpr int FPL = D / 64;      // features per lane (8 or 4)
    constexpr int UPL = FPL / 2;     // uints per lane
    int node = blockIdx.x * 4 + (threadIdx.x >> 6);
    int lane = threadIdx.x & 63;
    if (node >= N_NODES) return;
    const unsigned* hrow = (const unsigned*)(h + (size_t)node * D + lane * FPL);
    float acc[FPL];
    float sl = nloop[node];
    unsigned tmp[UPL];
#pragma unroll
    for (int u = 0; u < UPL; ++u) tmp[u] = hrow[u];
#pragma unroll
    for (int u = 0; u < UPL; ++u) {
        acc[2 * u]     = __uint_as_float(tmp[u] << 16) * sl;
        acc[2 * u + 1] = __uint_as_float(tmp[u] & 0xFFFF0000u) * sl;
    }
    int beg = rowptr[node], end = rowptr[node + 1];
    for (int j = beg; j < end; ++j) {
        int s = col[j];
        float v = val[j];
        const unsigned* xr = (const unsigned*)(h + (size_t)s * D + lane * FPL);
#pragma unroll
        for (int u = 0; u < UPL; ++u) tmp[u] = xr[u];
#pragma unroll
        for (int u = 0; u < UPL; ++u) {
            acc[2 * u]     += __uint_as_float(tmp[u] << 16) * v;
            acc[2 * u + 1] += __uint_as_float(tmp[u] & 0xFFFF0000u) * v;
        }
    }
    unsigned* orow = (unsigned*)(out + (size_t)node * D + lane * FPL);
#pragma unroll
    for (int u = 0; u < UPL; ++u) {
        unsigned lo = f2bf(acc[2 * u]);
        unsigned hi = f2bf(acc[2 * u + 1]);
        orow[u] = lo | (hi << 16);
    }
}

// ---------------------------------------------------------------------------
// pooling (batch sorted): run-length local accumulation then atomicAdd
// ---------------------------------------------------------------------------
#define NP 50
__global__ void pool_sum_bf16(const unsigned short* __restrict__ x, const int* __restrict__ batch,
                              float* __restrict__ sums) {
    int t = blockIdx.x * blockDim.x + threadIdx.x;
    int total = (N_NODES / NP) * D_HID;
    if (t >= total) return;
    int d = t % D_HID;
    int group = t / D_HID;
    int n0 = group * NP;
    float acc = 0.f;
    int g = batch[n0];
    for (int k = 0; k < NP; ++k) {
        int n = n0 + k;
        int bg = batch[n];
        if (bg != g) { atomicAdd(&sums[(size_t)g * D_HID + d], acc); acc = 0.f; g = bg; }
        acc += bf2f(x[(size_t)n * D_HID + d]);
    }
    atomicAdd(&sums[(size_t)g * D_HID + d], acc);
}

__global__ void cnt_kernel(const int* __restrict__ batch, float* __restrict__ cnts) {
    int n = blockIdx.x * blockDim.x + threadIdx.x;
    if (n < N_NODES) atomicAdd(&cnts[batch[n]], 1.f);
}

__global__ void zero_kernel(float* __restrict__ p, int n) {
    int i = blockIdx.x * blockDim.x + threadIdx.x;
    if (i < n) p[i] = 0.f;
}

__global__ void fc1_kernel(const float* __restrict__ sums, const float* __restrict__ cnts,
                           const float* __restrict__ W, const float* __restrict__ b,
                           float* __restrict__ out) {
    int t = blockIdx.x * blockDim.x + threadIdx.x;
    if (t >= N_GRAPHS * D_FC) return;
    int j = t % D_FC, g = t / D_FC;
    float acc = 0.f;
    const float* srow = sums + (size_t)g * D_HID;
    for (int k = 0; k < D_HID; ++k) acc += srow[k] * W[(size_t)k * D_FC + j];
    float cdiv = fmaxf(cnts[g], 1.f);
    out[t] = fmaxf(acc / cdiv + b[j], 0.f);
}

__global__ void head_kernel(const float* __restrict__ f, const float* __restrict__ W,
                            const float* __restrict__ b, float* __restrict__ out) {
    int t = blockIdx.x * blockDim.x + threadIdx.x;
    if (t >= N_GRAPHS * N_CLS) return;
    int c = t % N_CLS, g = t / N_CLS;
    float acc = b[c];
    const float* fr = f + (size_t)g * D_FC;
    for (int j = 0; j < D_FC; ++j) acc += fr[j] * W[(size_t)j * N_CLS + c];
    out[t] = acc;
}

// ---------------------------------------------------------------------------
extern "C" void kernel_launch(void* const* d_in, const int* in_sizes, int n_in,
                              void* d_out, int out_size, void* d_ws, size_t ws_size,
                              hipStream_t stream) {
    const float* x          = (const float*)d_in[0];
    const int*   edge_index = (const int*)d_in[1];
    const float* edge_attr  = (const float*)d_in[2];
    const int*   batch      = (const int*)d_in[3];
    const float* emb_w1 = (const float*)d_in[4];
    const float* emb_b1 = (const float*)d_in[5];
    const float* emb_w2 = (const float*)d_in[6];
    const float* emb_b2 = (const float*)d_in[7];
    const float* ep_w1  = (const float*)d_in[8];
    const float* ep_b1  = (const float*)d_in[9];
    const float* ep_w2  = (const float*)d_in[10];
    const float* ep_b2  = (const float*)d_in[11];
    const float* w_c[6] = { (const float*)d_in[12], (const float*)d_in[14], (const float*)d_in[16],
                            (const float*)d_in[18], (const float*)d_in[20], (const float*)d_in[22] };
    const float* b_c[6] = { (const float*)d_in[13], (const float*)d_in[15], (const float*)d_in[17],
                            (const float*)d_in[19], (const float*)d_in[21], (const float*)d_in[23] };
    const float* fc1_w  = (const float*)d_in[24];
    const float* fc1_b  = (const float*)d_in[25];
    const float* head_w = (const float*)d_in[26];
    const float* head_b = (const float*)d_in[27];
    float* out = (float*)d_out;

    const int* src = edge_index;
    const int* dst = edge_index + N_EDGES;

    char* p = (char*)d_ws;
    auto alloc = [&](size_t bytes) { char* r = p; p += (bytes + 255) & ~(size_t)255; return r; };
    float* ew    = (float*)alloc(N_EDGES * 4);
    float* deg   = (float*)alloc(N_NODES * 4);
    float* dinv  = (float*)alloc(N_NODES * 4);
    float* nloop = (float*)alloc(N_NODES * 4);
    float* val   = (float*)alloc(N_EDGES * 4);
    int* cnt     = (int*)alloc(N_NODES * 4);
    int* cursor  = (int*)alloc(N_NODES * 4);
    int* rowptr  = (int*)alloc((N_NODES + 1) * 4);
    int* col     = (int*)alloc(N_EDGES * 4);
    typedef unsigned short u16;
    u16* xb = (u16*)alloc((size_t)MP * F_IN * 2);
    u16* H1 = (u16*)alloc((size_t)MP * D_EMB * 2);
    u16* H2 = (u16*)alloc((size_t)MP * D_EMB * 2);
    u16* G  = (u16*)alloc((size_t)MP * D_HID * 2);
    u16* S1 = (u16*)alloc((size_t)MP * D_HID * 2);
    u16* S2 = (u16*)alloc((size_t)MP * D_HID * 2);
    u16* Cb = (u16*)alloc((size_t)MP * D_HID * 2);
    u16* we1h = (u16*)alloc((size_t)F_IN * D_EMB * 2);
    u16* we1l = (u16*)alloc((size_t)F_IN * D_EMB * 2);
    u16* we2h = (u16*)alloc((size_t)D_EMB * D_EMB * 2);
    u16* we2l = (u16*)alloc((size_t)D_EMB * D_EMB * 2);
    u16* wch[6]; u16* wcl[6];
    wch[0] = (u16*)alloc((size_t)D_EMB * D_HID * 2);
    wcl[0] = (u16*)alloc((size_t)D_EMB * D_HID * 2);
    for (int i = 1; i < 6; ++i) {
        wch[i] = (u16*)alloc((size_t)D_HID * D_HID * 2);
        wcl[i] = (u16*)alloc((size_t)D_HID * D_HID * 2);
    }
    float* sums = (float*)alloc(N_GRAPHS * D_HID * 4);
    float* cnts = (float*)alloc(N_GRAPHS * 4);
    float* f1o  = (float*)alloc(N_GRAPHS * D_FC * 4);

    const int TB = 256;
    const int EB = (N_EDGES + TB - 1) / TB;
    const int NB = (N_NODES + TB - 1) / TB;

    // --- edge weights, degrees, CSR ---
    edge_mlp_kernel<<<EB, TB, 0, stream>>>(edge_attr, ep_w1, ep_b1, ep_w2, ep_b2, ew);
    deg_init_kernel<<<NB, TB, 0, stream>>>(deg);
    zero_int_kernel<<<(2 * N_NODES + TB - 1) / TB, TB, 0, stream>>>(cnt, 2 * N_NODES);
    deg_add_kernel<<<EB, TB, 0, stream>>>(dst, ew, deg, cnt);
    dinv_kernel<<<NB, TB, 0, stream>>>(deg, dinv, nloop);
    scan_kernel<<<1, 1024, 0, stream>>>(cnt, rowptr);
    fill_csr_kernel<<<EB, TB, 0, stream>>>(src, dst, ew, dinv, rowptr, cursor, col, val);

    // --- weight + input prep ---
    xprep_kernel<<<(MP * F_IN + TB - 1) / TB, TB, 0, stream>>>(x, xb);
    wprep_kernel<<<(F_IN * D_EMB + TB - 1) / TB, TB, 0, stream>>>(emb_w1, we1h, we1l, F_IN, D_EMB);
    wprep_kernel<<<(D_EMB * D_EMB + TB - 1) / TB, TB, 0, stream>>>(emb_w2, we2h, we2l, D_EMB, D_EMB);
    wprep_kernel<<<(D_EMB * D_HID + TB - 1) / TB, TB, 0, stream>>>(w_c[0], wch[0], wcl[0], D_EMB, D_HID);
    for (int i = 1; i < 6; ++i)
        wprep_kernel<<<(D_HID * D_HID + TB - 1) / TB, TB, 0, stream>>>(w_c[i], wch[i], wcl[i], D_HID, D_HID);

    const int MB = MP / 128;   // 313
    // --- embedding MLP ---
    mfma_gemm<<<dim3(MB, D_EMB / 128), 256, 0, stream>>>(xb, we1h, we1l, emb_b1, nullptr, H1, F_IN, D_EMB);
    mfma_gemm<<<dim3(MB, D_EMB / 128), 256, 0, stream>>>(H1, we2h, we2l, emb_b2, nullptr, H2, D_EMB, D_EMB);

    const int GG = (N_NODES + 3) / 4;
    // --- conv1 ---
    gather_bf16<D_EMB><<<GG, 256, 0, stream>>>(H2, rowptr, col, val, nloop, G);
    mfma_gemm<<<dim3(MB, D_HID / 128), 256, 0, stream>>>(G, wch[0], wcl[0], b_c[0], nullptr, S1, D_EMB, D_HID);
    // --- conv2 ---
    gather_bf16<D_HID><<<GG, 256, 0, stream>>>(S1, rowptr, col, val, nloop, G);
    mfma_gemm<<<dim3(MB, D_HID / 128), 256, 0, stream>>>(G, wch[1], wcl[1], b_c[1], nullptr, Cb, D_HID, D_HID);
    // --- conv3 (skip S1) ---
    gather_bf16<D_HID><<<GG, 256, 0, stream>>>(Cb, rowptr, col, val, nloop, G);
    mfma_gemm<<<dim3(MB, D_HID / 128), 256, 0, stream>>>(G, wch[2], wcl[2], b_c[2], S1, S2, D_HID, D_HID);
    // --- conv4 ---
    gather_bf16<D_HID><<<GG, 256, 0, stream>>>(S2, rowptr, col, val, nloop, G);
    mfma_gemm<<<dim3(MB, D_HID / 128), 256, 0, stream>>>(G, wch[3], wcl[3], b_c[3], nullptr, Cb, D_HID, D_HID);
    // --- conv5 ---
    gather_bf16<D_HID><<<GG, 256, 0, stream>>>(Cb, rowptr, col, val, nloop, G);
    mfma_gemm<<<dim3(MB, D_HID / 128), 256, 0, stream>>>(G, wch[4], wcl[4], b_c[4], nullptr, Cb, D_HID, D_HID);
    // --- conv6 (skip S2) ---
    gather_bf16<D_HID><<<GG, 256, 0, stream>>>(Cb, rowptr, col, val, nloop, G);
    mfma_gemm<<<dim3(MB, D_HID / 128), 256, 0, stream>>>(G, wch[5], wcl[5], b_c[5], S2, Cb, D_HID, D_HID);

    // --- pool + head ---
    zero_kernel<<<(N_GRAPHS * D_HID + N_GRAPHS + TB - 1) / TB, TB, 0, stream>>>(sums, N_GRAPHS * D_HID + N_GRAPHS);
    pool_sum_bf16<<<((N_NODES / NP) * D_HID + TB - 1) / TB, TB, 0, stream>>>(Cb, batch, sums);
    cnt_kernel<<<NB, TB, 0, stream>>>(batch, cnts);
    fc1_kernel<<<(N_GRAPHS * D_FC + TB - 1) / TB, TB, 0, stream>>>(sums, cnts, fc1_w, fc1_b, f1o);
    head_kernel<<<(N_GRAPHS * N_CLS + TB - 1) / TB, TB, 0, stream>>>(f1o, head_w, head_b, out);
}

// Round 4
// 1516.368 us; speedup vs baseline: 17.0731x; 1.1852x over previous
//
#include <hip/hip_runtime.h>
#include <math.h>

#define N_NODES 40000
#define MP      40064   // padded to 128*313
#define N_EDGES 640000
#define N_GRAPHS 64
#define F_IN 32
#define D_EMB 256
#define D_HID 512
#define D_FC 1024
#define N_CLS 10

typedef short bf16x8 __attribute__((ext_vector_type(8)));
typedef float f32x4  __attribute__((ext_vector_type(4)));

__device__ __forceinline__ float bf2f(unsigned short u) {
    return __uint_as_float(((unsigned)u) << 16);
}
__device__ __forceinline__ unsigned short f2bf(float f) {
    unsigned u = __float_as_uint(f);
    return (unsigned short)((u + 0x7FFF + ((u >> 16) & 1)) >> 16);
}
__device__ __forceinline__ void async16(void* lds, const void* g) {
    __builtin_amdgcn_global_load_lds((const __attribute__((address_space(1))) void*)g,
                                     (__attribute__((address_space(3))) void*)lds, 16, 0, 0);
}

// ---------------------------------------------------------------------------
// edge MLP: ew = sigmoid(relu(e*w1+b1) @ w2 + b2)
// ---------------------------------------------------------------------------
__global__ void edge_mlp_kernel(const float* __restrict__ edge_attr,
                                const float* __restrict__ ep_w1, const float* __restrict__ ep_b1,
                                const float* __restrict__ ep_w2, const float* __restrict__ ep_b2,
                                float* __restrict__ ew) {
    __shared__ float w1[64], b1[64], w2[64];
    int t = threadIdx.x;
    if (t < 64) { w1[t] = ep_w1[t]; b1[t] = ep_b1[t]; w2[t] = ep_w2[t]; }
    __syncthreads();
    int e = blockIdx.x * blockDim.x + t;
    if (e >= N_EDGES) return;
    float x = edge_attr[e];
    float s = ep_b2[0];
#pragma unroll
    for (int j = 0; j < 64; ++j) s += fmaxf(x * w1[j] + b1[j], 0.f) * w2[j];
    ew[e] = 1.f / (1.f + expf(-s));
}

__global__ void zero_int_kernel(int* __restrict__ p, int n) {
    int i = blockIdx.x * blockDim.x + threadIdx.x;
    if (i < n) p[i] = 0;
}

__global__ void deg_init_kernel(float* __restrict__ deg) {
    int i = blockIdx.x * blockDim.x + threadIdx.x;
    if (i < N_NODES) deg[i] = 1.0f;
}

__global__ void deg_add_kernel(const int* __restrict__ dst, const float* __restrict__ ew,
                               float* __restrict__ deg, int* __restrict__ cnt) {
    int e = blockIdx.x * blockDim.x + threadIdx.x;
    if (e >= N_EDGES) return;
    int d = dst[e];
    atomicAdd(&deg[d], ew[e]);
    atomicAdd(&cnt[d], 1);
}

__global__ void dinv_kernel(const float* __restrict__ deg, float* __restrict__ dinv,
                            float* __restrict__ nloop) {
    int i = blockIdx.x * blockDim.x + threadIdx.x;
    if (i >= N_NODES) return;
    float d = deg[i];
    float r = (d > 0.f) ? rsqrtf(fmaxf(d, 1e-12f)) : 0.f;
    dinv[i] = r;
    nloop[i] = r * r;
}

__global__ void scan_kernel(const int* __restrict__ cnt, int* __restrict__ rowptr) {
    __shared__ int part[1024];
    int t = threadIdx.x;
    const int PER = (N_NODES + 1023) / 1024;
    int base = t * PER;
    int s = 0;
    for (int k = 0; k < PER; ++k) { int i = base + k; if (i < N_NODES) s += cnt[i]; }
    part[t] = s;
    __syncthreads();
    for (int off = 1; off < 1024; off <<= 1) {
        int v = (t >= off) ? part[t - off] : 0;
        __syncthreads();
        part[t] += v;
        __syncthreads();
    }
    int run = (t == 0) ? 0 : part[t - 1];
    for (int k = 0; k < PER; ++k) {
        int i = base + k;
        if (i < N_NODES) { rowptr[i] = run; run += cnt[i]; }
    }
    if (t == 1023) rowptr[N_NODES] = run;
}

// fill CSR: packed (col, val) int2 per slot
__global__ void fill_csr_kernel(const int* __restrict__ src, const int* __restrict__ dst,
                                const float* __restrict__ ew, const float* __restrict__ dinv,
                                const int* __restrict__ rowptr, int* __restrict__ cursor,
                                int2* __restrict__ cv) {
    int e = blockIdx.x * blockDim.x + threadIdx.x;
    if (e >= N_EDGES) return;
    int d = dst[e];
    int s = src[e];
    float n = dinv[s] * ew[e] * dinv[d];
    int p = rowptr[d] + atomicAdd(&cursor[d], 1);
    cv[p] = make_int2(s, __float_as_int(n));
}

// ---------------------------------------------------------------------------
// weight prep: W[K][N] fp32 -> Wth/Wtl [N][K] bf16 (hi+lo split), LDS tiled.
// grid (N/32, K/32), block (32,8). K,N multiples of 32.
// ---------------------------------------------------------------------------
__global__ void wprep_kernel(const float* __restrict__ W, unsigned short* __restrict__ Wth,
                             unsigned short* __restrict__ Wtl, int K, int N) {
    __shared__ unsigned short th[32][33];
    __shared__ unsigned short tl[32][33];
    int n0 = blockIdx.x * 32;
    int k0 = blockIdx.y * 32;
    int tx = threadIdx.x, ty = threadIdx.y;
#pragma unroll
    for (int r = 0; r < 4; ++r) {
        int k = ty + r * 8;
        float w = W[(size_t)(k0 + k) * N + n0 + tx];
        unsigned short hi = f2bf(w);
        th[k][tx] = hi;
        tl[k][tx] = f2bf(w - bf2f(hi));
    }
    __syncthreads();
#pragma unroll
    for (int r = 0; r < 4; ++r) {
        int n = ty + r * 8;
        Wth[(size_t)(n0 + n) * K + k0 + tx] = th[tx][n];
        Wtl[(size_t)(n0 + n) * K + k0 + tx] = tl[tx][n];
    }
}

// x fp32 [N_NODES][F_IN] -> bf16 [MP][F_IN] (pad rows zeroed)
__global__ void xprep_kernel(const float* __restrict__ x, unsigned short* __restrict__ xb) {
    int idx = blockIdx.x * blockDim.x + threadIdx.x;
    if (idx >= MP * F_IN) return;
    int row = idx / F_IN;
    xb[idx] = (row < N_NODES) ? f2bf(x[idx]) : (unsigned short)0;
}

// ---------------------------------------------------------------------------
// MFMA GEMM: C[MP][N] = relu(A[MP][K]_bf16 @ (Wh+Wl)[K][N] + bias) (+skip)
// Wh/Wl transposed [N][K]. 128x128 tile, 256 thr (4 waves), BK=32.
// ---------------------------------------------------------------------------
__launch_bounds__(256)
__global__ void mfma_gemm(const unsigned short* __restrict__ A,
                          const unsigned short* __restrict__ Wh,
                          const unsigned short* __restrict__ Wl,
                          const float* __restrict__ bias,
                          const unsigned short* __restrict__ skip,
                          unsigned short* __restrict__ C, int K, int N) {
    __shared__ __align__(16) unsigned short As[128 * 32];
    __shared__ __align__(16) unsigned short Hs[128 * 32];
    __shared__ __align__(16) unsigned short Ls[128 * 32];
    int t = threadIdx.x;
    int lane = t & 63;
    int wave = t >> 6;
    int wr = wave >> 1, wc = wave & 1;
    int rowBase = blockIdx.x * 128;
    int colBase = blockIdx.y * 128;

    int r0 = wave * 32;
    int rr = r0 + (lane >> 2);
    int selem = (lane & 3) * 8;

    int quad = lane >> 4;
    int mrow = lane & 15;

    f32x4 acc[4][4] = {};

    for (int k0 = 0; k0 < K; k0 += 32) {
        const unsigned short* gA = A + (size_t)(rowBase + rr) * K + k0 + selem;
        const unsigned short* gH = Wh + (size_t)(colBase + rr) * K + k0 + selem;
        const unsigned short* gL = Wl + (size_t)(colBase + rr) * K + k0 + selem;
        async16(&As[r0 * 32], gA);
        async16(&As[(r0 + 16) * 32], gA + (size_t)16 * K);
        async16(&Hs[r0 * 32], gH);
        async16(&Hs[(r0 + 16) * 32], gH + (size_t)16 * K);
        async16(&Ls[r0 * 32], gL);
        async16(&Ls[(r0 + 16) * 32], gL + (size_t)16 * K);
        __syncthreads();

        bf16x8 af[4], hf[4], lf[4];
#pragma unroll
        for (int i = 0; i < 4; ++i) {
            af[i] = *(const bf16x8*)&As[(wr * 64 + i * 16 + mrow) * 32 + quad * 8];
            hf[i] = *(const bf16x8*)&Hs[(wc * 64 + i * 16 + mrow) * 32 + quad * 8];
            lf[i] = *(const bf16x8*)&Ls[(wc * 64 + i * 16 + mrow) * 32 + quad * 8];
        }
#pragma unroll
        for (int i = 0; i < 4; ++i)
#pragma unroll
            for (int j = 0; j < 4; ++j) {
                acc[i][j] = __builtin_amdgcn_mfma_f32_16x16x32_bf16(af[i], hf[j], acc[i][j], 0, 0, 0);
                acc[i][j] = __builtin_amdgcn_mfma_f32_16x16x32_bf16(af[i], lf[j], acc[i][j], 0, 0, 0);
            }
        __syncthreads();
    }

    int col0 = colBase + wc * 64 + mrow;
#pragma unroll
    for (int j = 0; j < 4; ++j) {
        int col = col0 + j * 16;
        float bv = bias[col];
#pragma unroll
        for (int i = 0; i < 4; ++i) {
#pragma unroll
            for (int r = 0; r < 4; ++r) {
                size_t row = (size_t)rowBase + wr * 64 + i * 16 + quad * 4 + r;
                float v = fmaxf(acc[i][j][r] + bv, 0.f);
                if (skip) v += bf2f(skip[row * N + col]);
                C[row * N + col] = f2bf(v);
            }
        }
    }
}

// ---------------------------------------------------------------------------
// gather aggregation (bf16 in/out, fp32 accum): one wave per node
// ---------------------------------------------------------------------------
template <int D>
__global__ void gather_bf16(const unsigned short* __restrict__ h, const int* __restrict__ rowptr,
                            const int2* __restrict__ cv, const float* __restrict__ nloop,
                            unsigned short* __restrict__ out) {
    constexpr int FPL = D / 64;
    constexpr int UPL = FPL / 2;
    int node = blockIdx.x * 4 + (threadIdx.x >> 6);
    int lane = threadIdx.x & 63;
    if (node >= N_NODES) return;
    const unsigned* hrow = (const unsigned*)(h + (size_t)node * D + lane * FPL);
    float acc[FPL];
    float sl = nloop[node];
    unsigned tmp[UPL];
#pragma unroll
    for (int u = 0; u < UPL; ++u) tmp[u] = hrow[u];
#pragma unroll
    for (int u = 0; u < UPL; ++u) {
        acc[2 * u]     = __uint_as_float(tmp[u] << 16) * sl;
        acc[2 * u + 1] = __uint_as_float(tmp[u] & 0xFFFF0000u) * sl;
    }
    int beg = rowptr[node], end = rowptr[node + 1];
    for (int j = beg; j < end; ++j) {
        int2 c = cv[j];
        float v = __int_as_float(c.y);
        const unsigned* xr = (const unsigned*)(h + (size_t)c.x * D + lane * FPL);
#pragma unroll
        for (int u = 0; u < UPL; ++u) tmp[u] = xr[u];
#pragma unroll
        for (int u = 0; u < UPL; ++u) {
            acc[2 * u]     += __uint_as_float(tmp[u] << 16) * v;
            acc[2 * u + 1] += __uint_as_float(tmp[u] & 0xFFFF0000u) * v;
        }
    }
    unsigned* orow = (unsigned*)(out + (size_t)node * D + lane * FPL);
#pragma unroll
    for (int u = 0; u < UPL; ++u) {
        unsigned lo = f2bf(acc[2 * u]);
        unsigned hi = f2bf(acc[2 * u + 1]);
        orow[u] = lo | (hi << 16);
    }
}

// ---------------------------------------------------------------------------
// pooling (batch sorted)
// ---------------------------------------------------------------------------
#define NP 50
__global__ void pool_sum_bf16(const unsigned short* __restrict__ x, const int* __restrict__ batch,
                              float* __restrict__ sums) {
    int t = blockIdx.x * blockDim.x + threadIdx.x;
    int total = (N_NODES / NP) * D_HID;
    if (t >= total) return;
    int d = t % D_HID;
    int group = t / D_HID;
    int n0 = group * NP;
    float acc = 0.f;
    int g = batch[n0];
    for (int k = 0; k < NP; ++k) {
        int n = n0 + k;
        int bg = batch[n];
        if (bg != g) { atomicAdd(&sums[(size_t)g * D_HID + d], acc); acc = 0.f; g = bg; }
        acc += bf2f(x[(size_t)n * D_HID + d]);
    }
    atomicAdd(&sums[(size_t)g * D_HID + d], acc);
}

// batch sorted ascending -> counts by binary search; one thread per graph
__global__ void graph_cnt_kernel(const int* __restrict__ batch, float* __restrict__ cnts) {
    int g = threadIdx.x;
    if (g >= N_GRAPHS) return;
    // lower bound of g
    int lo = 0, hi = N_NODES;
    while (lo < hi) { int m = (lo + hi) >> 1; if (batch[m] < g) lo = m + 1; else hi = m; }
    int lb = lo;
    // lower bound of g+1
    lo = lb; hi = N_NODES;
    while (lo < hi) { int m = (lo + hi) >> 1; if (batch[m] < g + 1) lo = m + 1; else hi = m; }
    cnts[g] = (float)(lo - lb);
}

__global__ void zero_kernel(float* __restrict__ p, int n) {
    int i = blockIdx.x * blockDim.x + threadIdx.x;
    if (i < n) p[i] = 0.f;
}

__global__ void fc1_kernel(const float* __restrict__ sums, const float* __restrict__ cnts,
                           const float* __restrict__ W, const float* __restrict__ b,
                           float* __restrict__ out) {
    int t = blockIdx.x * blockDim.x + threadIdx.x;
    if (t >= N_GRAPHS * D_FC) return;
    int j = t % D_FC, g = t / D_FC;
    float acc = 0.f;
    const float* srow = sums + (size_t)g * D_HID;
    for (int k = 0; k < D_HID; ++k) acc += srow[k] * W[(size_t)k * D_FC + j];
    float cdiv = fmaxf(cnts[g], 1.f);
    out[t] = fmaxf(acc / cdiv + b[j], 0.f);
}

__global__ void head_kernel(const float* __restrict__ f, const float* __restrict__ W,
                            const float* __restrict__ b, float* __restrict__ out) {
    int t = blockIdx.x * blockDim.x + threadIdx.x;
    if (t >= N_GRAPHS * N_CLS) return;
    int c = t % N_CLS, g = t / N_CLS;
    float acc = b[c];
    const float* fr = f + (size_t)g * D_FC;
    for (int j = 0; j < D_FC; ++j) acc += fr[j] * W[(size_t)j * N_CLS + c];
    out[t] = acc;
}

// ---------------------------------------------------------------------------
extern "C" void kernel_launch(void* const* d_in, const int* in_sizes, int n_in,
                              void* d_out, int out_size, void* d_ws, size_t ws_size,
                              hipStream_t stream) {
    const float* x          = (const float*)d_in[0];
    const int*   edge_index = (const int*)d_in[1];
    const float* edge_attr  = (const float*)d_in[2];
    const int*   batch      = (const int*)d_in[3];
    const float* emb_w1 = (const float*)d_in[4];
    const float* emb_b1 = (const float*)d_in[5];
    const float* emb_w2 = (const float*)d_in[6];
    const float* emb_b2 = (const float*)d_in[7];
    const float* ep_w1  = (const float*)d_in[8];
    const float* ep_b1  = (const float*)d_in[9];
    const float* ep_w2  = (const float*)d_in[10];
    const float* ep_b2  = (const float*)d_in[11];
    const float* w_c[6] = { (const float*)d_in[12], (const float*)d_in[14], (const float*)d_in[16],
                            (const float*)d_in[18], (const float*)d_in[20], (const float*)d_in[22] };
    const float* b_c[6] = { (const float*)d_in[13], (const float*)d_in[15], (const float*)d_in[17],
                            (const float*)d_in[19], (const float*)d_in[21], (const float*)d_in[23] };
    const float* fc1_w  = (const float*)d_in[24];
    const float* fc1_b  = (const float*)d_in[25];
    const float* head_w = (const float*)d_in[26];
    const float* head_b = (const float*)d_in[27];
    float* out = (float*)d_out;

    const int* src = edge_index;
    const int* dst = edge_index + N_EDGES;

    char* p = (char*)d_ws;
    auto alloc = [&](size_t bytes) { char* r = p; p += (bytes + 255) & ~(size_t)255; return r; };
    float* ew    = (float*)alloc(N_EDGES * 4);
    float* deg   = (float*)alloc(N_NODES * 4);
    float* dinv  = (float*)alloc(N_NODES * 4);
    float* nloop = (float*)alloc(N_NODES * 4);
    int* cnt     = (int*)alloc(N_NODES * 4);
    int* cursor  = (int*)alloc(N_NODES * 4);
    int* rowptr  = (int*)alloc((N_NODES + 1) * 4);
    int2* cv     = (int2*)alloc((size_t)N_EDGES * 8);
    typedef unsigned short u16;
    u16* xb = (u16*)alloc((size_t)MP * F_IN * 2);
    u16* H1 = (u16*)alloc((size_t)MP * D_EMB * 2);
    u16* H2 = (u16*)alloc((size_t)MP * D_EMB * 2);
    u16* G  = (u16*)alloc((size_t)MP * D_HID * 2);
    u16* S1 = (u16*)alloc((size_t)MP * D_HID * 2);
    u16* S2 = (u16*)alloc((size_t)MP * D_HID * 2);
    u16* Cb = (u16*)alloc((size_t)MP * D_HID * 2);
    u16* we1h = (u16*)alloc((size_t)F_IN * D_EMB * 2);
    u16* we1l = (u16*)alloc((size_t)F_IN * D_EMB * 2);
    u16* we2h = (u16*)alloc((size_t)D_EMB * D_EMB * 2);
    u16* we2l = (u16*)alloc((size_t)D_EMB * D_EMB * 2);
    u16* wch[6]; u16* wcl[6];
    wch[0] = (u16*)alloc((size_t)D_EMB * D_HID * 2);
    wcl[0] = (u16*)alloc((size_t)D_EMB * D_HID * 2);
    for (int i = 1; i < 6; ++i) {
        wch[i] = (u16*)alloc((size_t)D_HID * D_HID * 2);
        wcl[i] = (u16*)alloc((size_t)D_HID * D_HID * 2);
    }
    float* sums = (float*)alloc(N_GRAPHS * D_HID * 4);
    float* cnts = (float*)alloc(N_GRAPHS * 4);
    float* f1o  = (float*)alloc(N_GRAPHS * D_FC * 4);

    const int TB = 256;
    const int EB = (N_EDGES + TB - 1) / TB;
    const int NB = (N_NODES + TB - 1) / TB;

    // --- edge weights, degrees, CSR ---
    edge_mlp_kernel<<<EB, TB, 0, stream>>>(edge_attr, ep_w1, ep_b1, ep_w2, ep_b2, ew);
    deg_init_kernel<<<NB, TB, 0, stream>>>(deg);
    zero_int_kernel<<<(2 * N_NODES + TB - 1) / TB, TB, 0, stream>>>(cnt, 2 * N_NODES);
    deg_add_kernel<<<EB, TB, 0, stream>>>(dst, ew, deg, cnt);
    dinv_kernel<<<NB, TB, 0, stream>>>(deg, dinv, nloop);
    scan_kernel<<<1, 1024, 0, stream>>>(cnt, rowptr);
    fill_csr_kernel<<<EB, TB, 0, stream>>>(src, dst, ew, dinv, rowptr, cursor, cv);

    // --- weight + input prep ---
    xprep_kernel<<<(MP * F_IN + TB - 1) / TB, TB, 0, stream>>>(x, xb);
    wprep_kernel<<<dim3(D_EMB / 32, F_IN / 32), dim3(32, 8), 0, stream>>>(emb_w1, we1h, we1l, F_IN, D_EMB);
    wprep_kernel<<<dim3(D_EMB / 32, D_EMB / 32), dim3(32, 8), 0, stream>>>(emb_w2, we2h, we2l, D_EMB, D_EMB);
    wprep_kernel<<<dim3(D_HID / 32, D_EMB / 32), dim3(32, 8), 0, stream>>>(w_c[0], wch[0], wcl[0], D_EMB, D_HID);
    for (int i = 1; i < 6; ++i)
        wprep_kernel<<<dim3(D_HID / 32, D_HID / 32), dim3(32, 8), 0, stream>>>(w_c[i], wch[i], wcl[i], D_HID, D_HID);

    const int MB = MP / 128;
    // --- embedding MLP ---
    mfma_gemm<<<dim3(MB, D_EMB / 128), 256, 0, stream>>>(xb, we1h, we1l, emb_b1, nullptr, H1, F_IN, D_EMB);
    mfma_gemm<<<dim3(MB, D_EMB / 128), 256, 0, stream>>>(H1, we2h, we2l, emb_b2, nullptr, H2, D_EMB, D_EMB);

    const int GG = (N_NODES + 3) / 4;
    // --- conv1 ---
    gather_bf16<D_EMB><<<GG, 256, 0, stream>>>(H2, rowptr, cv, nloop, G);
    mfma_gemm<<<dim3(MB, D_HID / 128), 256, 0, stream>>>(G, wch[0], wcl[0], b_c[0], nullptr, S1, D_EMB, D_HID);
    // --- conv2 ---
    gather_bf16<D_HID><<<GG, 256, 0, stream>>>(S1, rowptr, cv, nloop, G);
    mfma_gemm<<<dim3(MB, D_HID / 128), 256, 0, stream>>>(G, wch[1], wcl[1], b_c[1], nullptr, Cb, D_HID, D_HID);
    // --- conv3 (skip S1) ---
    gather_bf16<D_HID><<<GG, 256, 0, stream>>>(Cb, rowptr, cv, nloop, G);
    mfma_gemm<<<dim3(MB, D_HID / 128), 256, 0, stream>>>(G, wch[2], wcl[2], b_c[2], S1, S2, D_HID, D_HID);
    // --- conv4 ---
    gather_bf16<D_HID><<<GG, 256, 0, stream>>>(S2, rowptr, cv, nloop, G);
    mfma_gemm<<<dim3(MB, D_HID / 128), 256, 0, stream>>>(G, wch[3], wcl[3], b_c[3], nullptr, Cb, D_HID, D_HID);
    // --- conv5 ---
    gather_bf16<D_HID><<<GG, 256, 0, stream>>>(Cb, rowptr, cv, nloop, G);
    mfma_gemm<<<dim3(MB, D_HID / 128), 256, 0, stream>>>(G, wch[4], wcl[4], b_c[4], nullptr, Cb, D_HID, D_HID);
    // --- conv6 (skip S2) ---
    gather_bf16<D_HID><<<GG, 256, 0, stream>>>(Cb, rowptr, cv, nloop, G);
    mfma_gemm<<<dim3(MB, D_HID / 128), 256, 0, stream>>>(G, wch[5], wcl[5], b_c[5], S2, Cb, D_HID, D_HID);

    // --- pool + head ---
    zero_kernel<<<(N_GRAPHS * D_HID + TB - 1) / TB, TB, 0, stream>>>(sums, N_GRAPHS * D_HID);
    pool_sum_bf16<<<((N_NODES / NP) * D_HID + TB - 1) / TB, TB, 0, stream>>>(Cb, batch, sums);
    graph_cnt_kernel<<<1, 64, 0, stream>>>(batch, cnts);
    fc1_kernel<<<(N_GRAPHS * D_FC + TB - 1) / TB, TB, 0, stream>>>(sums, cnts, fc1_w, fc1_b, f1o);
    head_kernel<<<(N_GRAPHS * N_CLS + TB - 1) / TB, TB, 0, stream>>>(f1o, head_w, head_b, out);
}